// Round 18
// baseline (89.268 us; speedup 1.0000x reference)
//
#include <hip/hip_runtime.h>

// ---------------------------------------------------------------------------
// Attention fused for MI355X (gfx950)
//   x:[4,4096,1024] f32, Wq/Wk/Wv:[128,1024] f32 -> out:[4,4096,128] f32
// Round 18: qkv -> N-split-3 (ns=q/k/v, BN=128), 48KB LDS = 3 blocks/CU
//   (12 waves/CU vs 8), same R11 drain-free schedule + clean 128B rows.
//   XCD grouping: 3 ns-splits of an m-tile dispatch-adjacent per XCD.
//   attn/wconv/combine = round-17 byte-identical (best measured).
// ws: [0,4M) q bf16 (scaled), [4M,8M) k bf16, [8M,12M) v^T bf16 [B][128][T],
//     [12M,12.75M) W bf16, [13M,~44.2M) o partials f32 [476][128][128],
//     [47M,~47.5M) m,l partials f32 [2][476][128].
// ---------------------------------------------------------------------------

typedef __attribute__((ext_vector_type(8))) short short8;
typedef __attribute__((ext_vector_type(8))) unsigned short ushort8;
typedef __attribute__((ext_vector_type(4))) unsigned short ushort4v;
typedef __attribute__((ext_vector_type(4))) float f32x4;
typedef __attribute__((ext_vector_type(16))) float f32x16;
typedef __attribute__((ext_vector_type(4))) int int4v;
typedef unsigned int u32;
typedef unsigned short u16;

#define MFMA32(a, b, c) __builtin_amdgcn_mfma_f32_32x32x16_bf16((a), (b), (c), 0, 0, 0)
#define WAITVM0() asm volatile("s_waitcnt vmcnt(0)" ::: "memory")
#define WAITLGKM0() asm volatile("s_waitcnt lgkmcnt(0)" ::: "memory")
#define SCHEDB() __builtin_amdgcn_sched_barrier(0)
#define NEG_INF (-1e30f)

#define CHUNK 10            // kv-steps (of 64) per attn work item
#define PITEMS 119          // items per batch = sum_{qt<32} ceil((qt+1)/5)
#define NITEMS 476          // 4 * PITEMS

__device__ __forceinline__ void gload16(const void* g, void* l) {
  __builtin_amdgcn_global_load_lds((const __attribute__((address_space(1))) u32*)g,
                                   (__attribute__((address_space(3))) u32*)l, 16, 0, 0);
}

__device__ __forceinline__ u16 f2bf(float f) {  // f32 -> bf16 bits, RNE
  u32 u = __builtin_bit_cast(u32, f);
  u = u + 0x7FFFu + ((u >> 16) & 1u);
  return (u16)(u >> 16);
}

__device__ __forceinline__ u32 cvtpk(float lo, float hi) {  // {bf16(lo),bf16(hi)}
  u32 r;
  asm("v_cvt_pk_bf16_f32 %0, %1, %2" : "=v"(r) : "v"(lo), "v"(hi));
  return r;
}

// ---------------- kernel 0: W f32 -> bf16 (Wb[384][1024]) -------------------
__global__ __launch_bounds__(256) void wconv_kernel(const float* __restrict__ Wq,
                                                    const float* __restrict__ Wk,
                                                    const float* __restrict__ Wv,
                                                    u16* __restrict__ Wb) {
  int g = (blockIdx.x * 256 + threadIdx.x) * 8;
  const float* src;
  if (g < 131072)      src = Wq + g;
  else if (g < 262144) src = Wk + (g - 131072);
  else                 src = Wv + (g - 262144);
  float4 a = *(const float4*)src;
  float4 b = *(const float4*)(src + 4);
  ushort8 o;
  o[0] = f2bf(a.x); o[1] = f2bf(a.y); o[2] = f2bf(a.z); o[3] = f2bf(a.w);
  o[4] = f2bf(b.x); o[5] = f2bf(b.y); o[6] = f2bf(b.z); o[7] = f2bf(b.w);
  *(ushort8*)(Wb + g) = o;
}

// ---------------- kernel 1: fused QKV projection (N-split-3, 12 waves/CU) ---
// grid 768: xcd=bx&7, t=bx>>3, ns=t%3 (0:q 1:k 2:v), mt=xcd*32+t/3, m0=mt*64.
// 256 thr = 4 waves: wm=w>>1 (32-row half), wn=w&1 (2 n-tiles of the 4).
// W slice [128][64] bf16 dbuf; X [64][64] bf16 dbuf; 48KB LDS; drain-free
// R11 schedule (loads 3 ahead, 1 lgkmcnt(0)+barrier per step).
#define QK_SCALE 0.127517446f  // (1/sqrt(128)) * log2(e)

__global__ __launch_bounds__(256, 3) void qkv_proj_kernel(const float* __restrict__ x,
                                                          const u16* __restrict__ Wb,
                                                          u16* __restrict__ qout,
                                                          u16* __restrict__ kout,
                                                          u16* __restrict__ vtout) {
  __shared__ __align__(16) unsigned char Wlds[2][16384];  // [128][64] bf16 swz
  __shared__ __align__(16) unsigned char Xlds[2][8192];   // [64][64] bf16 swz
  const int tid = threadIdx.x;
  const int w = tid >> 6;
  const int l = tid & 63;
  const int h = l >> 5, n32 = l & 31;
  const int wm = w >> 1, wn = w & 1;
  const int bx = (int)blockIdx.x;
  const int xcd = bx & 7, tt = bx >> 3;     // 3 ns of one m-tile adjacent/XCD
  const int ns = tt % 3;                    // 0:q 1:k 2:v
  const int mt = xcd * 32 + tt / 3;         // 0..255
  const int m0 = mt * 64;

  // x staging: row xr (0..63), 16 consecutive f32 at col xc*16
  const int xr = tid >> 2, xc = tid & 3;
  const float* xsrc = x + (size_t)(m0 + xr) * 1024 + xc * 16;
  const int xsw = (xr & 7) << 4;
  const int xo0 = xr * 128 + ((xc * 32) ^ xsw);
  const int xo1 = xr * 128 + ((xc * 32 + 16) ^ xsw);
  // W staging: 4 chunks of 16B; row = (c*256+tid)>>3 in [0,128)
  const u16* wg[4];
  int wo[4];
#pragma unroll
  for (int c = 0; c < 4; ++c) {
    int L = c * 256 + tid;
    int row = L >> 3, chp = L & 7;
    wg[c] = Wb + (size_t)(ns * 128 + row) * 1024 + chp * 8;  // + ks*64 later
    wo[c] = row * 128 + ((chp * 16) ^ ((row & 7) << 4));
  }

  f32x16 acc[2];
#pragma unroll
  for (int j = 0; j < 2; ++j)
#pragma unroll
    for (int r = 0; r < 16; ++r) acc[j][r] = 0.f;

#define LOADS(S, k)                                                            \
  x##S##0 = *(const float4*)(xsrc + (k) * 64);                                 \
  x##S##1 = *(const float4*)(xsrc + (k) * 64 + 4);                             \
  x##S##2 = *(const float4*)(xsrc + (k) * 64 + 8);                             \
  x##S##3 = *(const float4*)(xsrc + (k) * 64 + 12);                            \
  w##S##0 = *(const ushort8*)(wg[0] + (k) * 64);                               \
  w##S##1 = *(const ushort8*)(wg[1] + (k) * 64);                               \
  w##S##2 = *(const ushort8*)(wg[2] + (k) * 64);                               \
  w##S##3 = *(const ushort8*)(wg[3] + (k) * 64);

#define WRITES(S, buf)                                                         \
  {                                                                            \
    float4 t0 = x##S##0;                                                       \
    float4 t1 = x##S##1;                                                       \
    float4 t2 = x##S##2;                                                       \
    float4 t3 = x##S##3;                                                       \
    ushort8 u0 = w##S##0;                                                      \
    ushort8 u1 = w##S##1;                                                      \
    ushort8 u2 = w##S##2;                                                      \
    ushort8 u3 = w##S##3;                                                      \
    int4v p0, p1;                                                              \
    p0[0] = (int)cvtpk(t0.x, t0.y);                                            \
    p0[1] = (int)cvtpk(t0.z, t0.w);                                            \
    p0[2] = (int)cvtpk(t1.x, t1.y);                                            \
    p0[3] = (int)cvtpk(t1.z, t1.w);                                            \
    p1[0] = (int)cvtpk(t2.x, t2.y);                                            \
    p1[1] = (int)cvtpk(t2.z, t2.w);                                            \
    p1[2] = (int)cvtpk(t3.x, t3.y);                                            \
    p1[3] = (int)cvtpk(t3.z, t3.w);                                            \
    *(int4v*)((unsigned char*)Xlds[buf] + xo0) = p0;                           \
    *(int4v*)((unsigned char*)Xlds[buf] + xo1) = p1;                           \
    *(ushort8*)((unsigned char*)Wlds[buf] + wo[0]) = u0;                       \
    *(ushort8*)((unsigned char*)Wlds[buf] + wo[1]) = u1;                       \
    *(ushort8*)((unsigned char*)Wlds[buf] + wo[2]) = u2;                       \
    *(ushort8*)((unsigned char*)Wlds[buf] + wo[3]) = u3;                       \
  }

#define COMPUTE(buf)                                                           \
  {                                                                            \
    const char* xb0 = (const char*)Xlds[buf];                                  \
    const char* wb0 = (const char*)Wlds[buf];                                  \
    __builtin_amdgcn_s_setprio(1);                                             \
    _Pragma("unroll") for (int k16 = 0; k16 < 4; ++k16) {                      \
      short8 a = *(const short8*)(xb0 + am * 128 +                             \
                                  ((k16 * 32 + h * 16) ^ asw));                \
      _Pragma("unroll") for (int j = 0; j < 2; ++j) {                          \
        int nrow = (wn * 2 + j) * 32 + n32;                                    \
        short8 b = *(const short8*)(wb0 + nrow * 128 +                         \
                                    ((k16 * 32 + h * 16) ^ ((nrow & 7) << 4)));\
        acc[j] = MFMA32(a, b, acc[j]);                                         \
      }                                                                        \
    }                                                                          \
    __builtin_amdgcn_s_setprio(0);                                             \
  }

  const int am = wm * 32 + n32;          // this lane's A row in the 64-tile
  const int asw = (am & 7) << 4;

  float4 xA0, xA1, xA2, xA3, xB0, xB1, xB2, xB3;
  ushort8 wA0, wA1, wA2, wA3, wB0, wB1, wB2, wB3;

  LOADS(A, 0);
  LOADS(B, 1);
  WRITES(A, 0);                          // auto-waits data0 loads only
  LOADS(A, 2);
  SCHEDB();

  for (int s = 0; s < 16; s += 2) {
    // ---- even step s: compute buf0 (data s) ----
    WAITLGKM0();
    SCHEDB();
    __builtin_amdgcn_s_barrier();        // buf0 = data(s) visible to all
    SCHEDB();
    WRITES(B, 1);                        // data(s+1) -> buf1
    if (s + 3 < 16) { LOADS(B, s + 3); }
    SCHEDB();
    COMPUTE(0);
    // ---- odd step s+1: compute buf1 (data s+1) ----
    WAITLGKM0();
    SCHEDB();
    __builtin_amdgcn_s_barrier();        // buf1 visible
    SCHEDB();
    if (s + 2 < 16) { WRITES(A, 0); }    // data(s+2) -> buf0
    if (s + 4 < 16) { LOADS(A, s + 4); }
    SCHEDB();
    COMPUTE(1);
  }
#undef LOADS
#undef WRITES
#undef COMPUTE

  // epilogue: C layout col=lane&31, row=(r&3)+8*(r>>2)+4h. Direct stores.
  const int m0e = m0 + wm * 32;
#pragma unroll
  for (int j = 0; j < 2; ++j) {
    int gcol = (wn * 2 + j) * 32 + n32;  // 0..127 within this ns
    if (ns == 0) {                       // q (scaled)
#pragma unroll
      for (int r = 0; r < 16; ++r) {
        int row = m0e + (r & 3) + 8 * (r >> 2) + 4 * h;
        qout[(size_t)row * 128 + gcol] = f2bf(acc[j][r] * QK_SCALE);
      }
    } else if (ns == 1) {                // k
#pragma unroll
      for (int r = 0; r < 16; ++r) {
        int row = m0e + (r & 3) + 8 * (r >> 2) + 4 * h;
        kout[(size_t)row * 128 + gcol] = f2bf(acc[j][r]);
      }
    } else {                             // v -> v^T [B][128][T], 4 consec t
#pragma unroll
      for (int rq = 0; rq < 4; ++rq) {
        int t0 = m0e + rq * 8 + 4 * h;
        ushort4v o4;
#pragma unroll
        for (int i = 0; i < 4; ++i) o4[i] = f2bf(acc[j][rq * 4 + i]);
        *(ushort4v*)&vtout[(size_t)((t0 >> 12) * 128 + gcol) * 4096 + (t0 & 4095)] = o4;
      }
    }
  }
}

// ---------------- kernel 2: causal flash attention (R17 verbatim) -----------
template <bool SPLIT>
__global__ __launch_bounds__(256, 2) void attn_kernel(const u16* __restrict__ qws,
                                                      const u16* __restrict__ kws,
                                                      const u16* __restrict__ vtws,
                                                      float* __restrict__ out,
                                                      float* __restrict__ opart,
                                                      float* __restrict__ mlpart) {
  __shared__ __align__(16) unsigned char Klds[2][16384];  // [64 kv][128 d] swz
  __shared__ __align__(16) unsigned char Vlds[2][16384];  // [128 d][64 kv] swz

  const int tid = threadIdx.x;
  const int w = tid >> 6;
  const int l = tid & 63;
  const int h = l >> 5, q32 = l & 31;

  int bi, qt, s_lo, s_hi, item;
  if constexpr (SPLIT) {
    // m204 bijective chunked XCD swizzle: NITEMS=476 -> q=59, r=4.
    int bx = (int)blockIdx.x;
    int xcd = bx & 7, t = bx >> 3;
    item = (xcd < 4 ? xcd * 60 : 240 + (xcd - 4) * 59) + t;   // 0..475
    bi = item / PITEMS;
    int r = item - bi * PITEMS;
    int base = 0;
    qt = 0;
    while (true) {                          // <=32 trivial iterations
      int cnt = (qt + 5) / 5;               // ceil((qt+1)/5) chunks for tile qt
      if (r < base + cnt) { break; }
      base += cnt;
      ++qt;
    }
    int cc = r - base;
    int nsteps = 2 * qt + 2;
    s_lo = cc * CHUNK;
    s_hi = (s_lo + CHUNK < nsteps) ? s_lo + CHUNK : nsteps;
  } else {
    item = 0;
    int tb = (int)blockIdx.x;
    bi = tb & 3;
    qt = 31 - (tb >> 2);
    s_lo = 0;
    s_hi = 2 * qt + 2;
  }

  const int q0w = qt * 128 + w * 32;
  const int qg = q0w + q32;
  const int grow = bi * 4096 + qg;          // this lane's global q row
  const int ql = w * 32 + q32;              // row within the 128-row tile

  // Q B-frags resident: col=q32, k = ks*16 + 8h + e
  short8 qf[8];
  const u16* qp = qws + (size_t)grow * 128 + h * 8;
#pragma unroll
  for (int ks = 0; ks < 8; ++ks) qf[ks] = *(const short8*)(qp + ks * 16);

  f32x16 ot[4];
#pragma unroll
  for (int dt = 0; dt < 4; ++dt)
#pragma unroll
    for (int r = 0; r < 16; ++r) ot[dt][r] = 0.f;
  float mreg = NEG_INF, lsum = 0.f;

  const char* kbatch = (const char*)kws + (size_t)bi * 4096 * 256;
  const char* vbatch = (const char*)vtws + (size_t)bi * 128 * 8192;

#define STAGE_KV(buf, kv0)                                                     \
  {                                                                            \
    _Pragma("unroll") for (int c = 0; c < 4; ++c) {                            \
      int L = c * 256 + tid;                                                   \
      int row = L >> 4, chp = L & 15;                                          \
      int gch = chp ^ (row & 7);                                               \
      gload16(kbatch + (size_t)((kv0) + row) * 256 + gch * 16,                 \
              (unsigned char*)Klds[buf] + c * 4096 + w * 1024);                \
    }                                                                          \
    _Pragma("unroll") for (int c = 0; c < 4; ++c) {                            \
      int L = c * 256 + tid;                                                   \
      int row = L >> 3, chp = L & 7;                                           \
      int gch = chp ^ (row & 7);                                               \
      gload16(vbatch + (size_t)row * 8192 + (size_t)(kv0) * 2 + gch * 16,      \
              (unsigned char*)Vlds[buf] + c * 4096 + w * 1024);                \
    }                                                                          \
  }

  STAGE_KV(0, s_lo * 64);
  int cur = 0;

  for (int s = s_lo; s < s_hi; ++s) {
    WAITVM0();                       // buf(cur) landed (own loads)
    __builtin_amdgcn_s_barrier();    // all waves drained + done with buf(cur^1)
    __builtin_amdgcn_sched_barrier(0);
    if (s + 1 < s_hi) STAGE_KV(cur ^ 1, (s + 1) * 64);
    const int kv0 = s * 64;
    const bool active = (kv0 <= q0w + 31);  // wave-uniform

    if (active) {
      // ---- S^T = K · Q^T : rows kv, cols q ----
      f32x16 st0, st1;
#pragma unroll
      for (int r = 0; r < 16; ++r) { st0[r] = 0.f; st1[r] = 0.f; }
      const char* Kb = (const char*)Klds[cur];
      const int sw = (q32 & 7) << 4;
      __builtin_amdgcn_s_setprio(1);
#pragma unroll
      for (int ks = 0; ks < 8; ++ks) {
        int coff = ks * 32 + h * 16;
        short8 a0 = *(const short8*)(Kb + q32 * 256 + (coff ^ sw));
        st0 = MFMA32(a0, qf[ks], st0);
        short8 a1 = *(const short8*)(Kb + (32 + q32) * 256 + (coff ^ sw));
        st1 = MFMA32(a1, qf[ks], st1);
      }
      __builtin_amdgcn_s_setprio(0);

      // ---- causal mask: kv > q -> -inf ----
      if (kv0 + 63 > q0w) {
#pragma unroll
        for (int r = 0; r < 16; ++r) {
          int kvr = kv0 + (r & 3) + 8 * (r >> 2) + 4 * h;
          if (kvr > qg) st0[r] = NEG_INF;
          if (kvr + 32 > qg) st1[r] = NEG_INF;
        }
      }

      // ---- online softmax (exp2 domain), defer-max THR=8 ----
      float tmax = st0[0];
#pragma unroll
      for (int r = 1; r < 16; ++r) tmax = fmaxf(tmax, st0[r]);
#pragma unroll
      for (int r = 0; r < 16; ++r) tmax = fmaxf(tmax, st1[r]);
      tmax = fmaxf(tmax, __shfl_xor(tmax, 32));
      if (!__all(tmax <= mreg + 8.0f)) {
        float mnew = fmaxf(mreg, tmax);
        float alpha = exp2f(mreg - mnew);
        lsum *= alpha;
#pragma unroll
        for (int dt = 0; dt < 4; ++dt)
#pragma unroll
          for (int r = 0; r < 16; ++r) ot[dt][r] *= alpha;
        mreg = mnew;
      }
      float rs = 0.f;
#pragma unroll
      for (int r = 0; r < 16; ++r) { st0[r] = exp2f(st0[r] - mreg); rs += st0[r]; }
#pragma unroll
      for (int r = 0; r < 16; ++r) { st1[r] = exp2f(st1[r] - mreg); rs += st1[r]; }
      rs += __shfl_xor(rs, 32);
      lsum += rs;

      // ---- O^T += V^T · P^T : per kv-16 tile build P B-frag in-register ----
      const char* Vb = (const char*)Vlds[cur];
      __builtin_amdgcn_s_setprio(1);
#pragma unroll
      for (int t = 0; t < 4; ++t) {
        const f32x16& stt = (t < 2) ? st0 : st1;
        const int rb = (t & 1) * 8;
        u32 A0 = cvtpk(stt[rb + 0], stt[rb + 1]);
        u32 C0 = cvtpk(stt[rb + 2], stt[rb + 3]);
        u32 B0 = cvtpk(stt[rb + 4], stt[rb + 5]);
        u32 D0 = cvtpk(stt[rb + 6], stt[rb + 7]);
        u32 Ax = (u32)__shfl_xor((int)A0, 32);
        u32 Bx = (u32)__shfl_xor((int)B0, 32);
        u32 Cx = (u32)__shfl_xor((int)C0, 32);
        u32 Dx = (u32)__shfl_xor((int)D0, 32);
        int4v pbv;
        pbv[0] = (int)(h ? Bx : A0);
        pbv[1] = (int)(h ? Dx : C0);
        pbv[2] = (int)(h ? B0 : Ax);
        pbv[3] = (int)(h ? D0 : Cx);
        short8 pb = __builtin_bit_cast(short8, pbv);
#pragma unroll
        for (int dt = 0; dt < 4; ++dt) {
          int row = dt * 32 + q32;
          short8 va = *(const short8*)(Vb + row * 128 + ((t * 32 + h * 16) ^ sw));
          ot[dt] = MFMA32(va, pb, ot[dt]);
        }
      }
      __builtin_amdgcn_s_setprio(0);
    }
    cur ^= 1;
  }

  if constexpr (!SPLIT) {
    float inv = 1.0f / lsum;
    float* ob = out + (size_t)grow * 128;
#pragma unroll
    for (int dt = 0; dt < 4; ++dt)
#pragma unroll
      for (int rq = 0; rq < 4; ++rq) {
        f32x4 v4;
#pragma unroll
        for (int i = 0; i < 4; ++i) v4[i] = ot[dt][rq * 4 + i] * inv;
        *(f32x4*)(ob + dt * 32 + rq * 8 + 4 * h) = v4;
      }
  } else {
    float* ob = opart + (size_t)item * 16384 + (size_t)ql * 128;
#pragma unroll
    for (int dt = 0; dt < 4; ++dt)
#pragma unroll
      for (int rq = 0; rq < 4; ++rq) {
        f32x4 v4;
#pragma unroll
        for (int i = 0; i < 4; ++i) v4[i] = ot[dt][rq * 4 + i];
        *(f32x4*)(ob + dt * 32 + rq * 8 + 4 * h) = v4;
      }
    if (h == 0) {
      mlpart[item * 128 + ql] = mreg;
      mlpart[NITEMS * 128 + item * 128 + ql] = lsum;
    }
  }
#undef STAGE_KV
}

// ---------------- kernel 3: variable-split combine (R17 verbatim) -----------
__global__ __launch_bounds__(256) void combine_kernel(const float* __restrict__ opart,
                                                      const float* __restrict__ mlpart,
                                                      float* __restrict__ out) {
  int idx = blockIdx.x * 256 + threadIdx.x;  // 16384*128 threads
  int row = idx >> 7, d = idx & 127;
  int bi = row >> 12, lrow = row & 4095;
  int qt = lrow >> 7, ql = lrow & 127;
  int base = 0;
#pragma unroll 1
  for (int j = 0; j < qt; ++j) base += (j + 5) / 5;
  int nspl = (qt + 5) / 5;
  int it0 = bi * PITEMS + base;

  float M = NEG_INF;
#pragma unroll 1
  for (int j = 0; j < nspl; ++j)
    M = fmaxf(M, mlpart[(it0 + j) * 128 + ql]);
  float L = 0.f, O = 0.f;
#pragma unroll 1
  for (int j = 0; j < nspl; ++j) {
    float s = exp2f(mlpart[(it0 + j) * 128 + ql] - M);
    L += mlpart[NITEMS * 128 + (it0 + j) * 128 + ql] * s;
    O += opart[(size_t)(it0 + j) * 16384 + (size_t)ql * 128 + d] * s;
  }
  out[(size_t)row * 128 + d] = O / L;
}

// ---------------------------------------------------------------------------
extern "C" void kernel_launch(void* const* d_in, const int* in_sizes, int n_in,
                              void* d_out, int out_size, void* d_ws, size_t ws_size,
                              hipStream_t stream) {
  (void)in_sizes; (void)n_in; (void)out_size;
  const float* x  = (const float*)d_in[0];
  const float* Wq = (const float*)d_in[1];
  const float* Wk = (const float*)d_in[2];
  const float* Wv = (const float*)d_in[3];
  float* out = (float*)d_out;
  char* ws = (char*)d_ws;
  u16* qws  = (u16*)(ws);
  u16* kws  = (u16*)(ws + (4u << 20));
  u16* vtws = (u16*)(ws + (8u << 20));
  u16* Wb   = (u16*)(ws + (12u << 20));
  float* opart  = (float*)(ws + (13u << 20));   // 476*64KB = 29.75 MiB
  float* mlpart = (float*)(ws + (47u << 20));   // 2*476*128*4B = 476 KiB

  wconv_kernel<<<dim3(192), dim3(256), 0, stream>>>(Wq, Wk, Wv, Wb);
  qkv_proj_kernel<<<dim3(768), dim3(256), 0, stream>>>(x, Wb, qws, kws, vtws);
  if (ws_size >= ((size_t)48 << 20)) {
    attn_kernel<true><<<dim3(NITEMS), dim3(256), 0, stream>>>(qws, kws, vtws, nullptr, opart, mlpart);
    combine_kernel<<<dim3(8192), dim3(256), 0, stream>>>(opart, mlpart, out);
  } else {
    attn_kernel<false><<<dim3(128), dim3(256), 0, stream>>>(qws, kws, vtws, out, nullptr, nullptr);
  }
}

// Round 19
// 87.660 us; speedup vs baseline: 1.0183x; 1.0183x over previous
//
#include <hip/hip_runtime.h>

// ---------------------------------------------------------------------------
// Attention fused for MI355X (gfx950)
//   x:[4,4096,1024] f32, Wq/Wk/Wv:[128,1024] f32 -> out:[4,4096,128] f32
// FINAL (= round 17, best measured 87.7 us):
//   wconv: W f32->bf16 (3 us).
//   qkv: drain-free reg-staged GEMM, BM=64/BN=192 N-split-2 + XCD pairing,
//        2 LDS bufs, 1 lgkmcnt(0)+s_barrier per K-step, loads 3 ahead (40 us;
//        pinned across 8 schedule/occupancy variants R2..R18).
//   attn: 4-wave 128-row q-tiles, KVBLK=64 K/V dbuf via global_load_lds,
//        1 WAITVM0+barrier per step, swapped QK^T 32x32 MFMA with in-register
//        softmax (exp2, defer-max THR=8), cvt_pk+shfl P-transpose, uniform
//        10-step work items + m204 XCD-chunked swizzle (39.7 us; optimum of
//        {V-single, KVBLK32, streaming, 8-wave} family). combine: 6.5 us.
// ws: [0,4M) q bf16 (scaled), [4M,8M) k bf16, [8M,12M) v^T bf16 [B][128][T],
//     [12M,12.75M) W bf16, [13M,~44.2M) o partials f32 [476][128][128],
//     [47M,~47.5M) m,l partials f32 [2][476][128].
// ---------------------------------------------------------------------------

typedef __attribute__((ext_vector_type(8))) short short8;
typedef __attribute__((ext_vector_type(8))) unsigned short ushort8;
typedef __attribute__((ext_vector_type(4))) unsigned short ushort4v;
typedef __attribute__((ext_vector_type(4))) float f32x4;
typedef __attribute__((ext_vector_type(16))) float f32x16;
typedef __attribute__((ext_vector_type(4))) int int4v;
typedef unsigned int u32;
typedef unsigned short u16;

#define MFMA32(a, b, c) __builtin_amdgcn_mfma_f32_32x32x16_bf16((a), (b), (c), 0, 0, 0)
#define WAITVM0() asm volatile("s_waitcnt vmcnt(0)" ::: "memory")
#define WAITLGKM0() asm volatile("s_waitcnt lgkmcnt(0)" ::: "memory")
#define SCHEDB() __builtin_amdgcn_sched_barrier(0)
#define NEG_INF (-1e30f)

#define CHUNK 10            // kv-steps (of 64) per attn work item
#define PITEMS 119          // items per batch = sum_{qt<32} ceil((qt+1)/5)
#define NITEMS 476          // 4 * PITEMS

__device__ __forceinline__ void gload16(const void* g, void* l) {
  __builtin_amdgcn_global_load_lds((const __attribute__((address_space(1))) u32*)g,
                                   (__attribute__((address_space(3))) u32*)l, 16, 0, 0);
}

__device__ __forceinline__ u16 f2bf(float f) {  // f32 -> bf16 bits, RNE
  u32 u = __builtin_bit_cast(u32, f);
  u = u + 0x7FFFu + ((u >> 16) & 1u);
  return (u16)(u >> 16);
}

__device__ __forceinline__ u32 cvtpk(float lo, float hi) {  // {bf16(lo),bf16(hi)}
  u32 r;
  asm("v_cvt_pk_bf16_f32 %0, %1, %2" : "=v"(r) : "v"(lo), "v"(hi));
  return r;
}

// ---------------- kernel 0: W f32 -> bf16 (Wb[384][1024]) -------------------
__global__ __launch_bounds__(256) void wconv_kernel(const float* __restrict__ Wq,
                                                    const float* __restrict__ Wk,
                                                    const float* __restrict__ Wv,
                                                    u16* __restrict__ Wb) {
  int g = (blockIdx.x * 256 + threadIdx.x) * 8;
  const float* src;
  if (g < 131072)      src = Wq + g;
  else if (g < 262144) src = Wk + (g - 131072);
  else                 src = Wv + (g - 262144);
  float4 a = *(const float4*)src;
  float4 b = *(const float4*)(src + 4);
  ushort8 o;
  o[0] = f2bf(a.x); o[1] = f2bf(a.y); o[2] = f2bf(a.z); o[3] = f2bf(a.w);
  o[4] = f2bf(b.x); o[5] = f2bf(b.y); o[6] = f2bf(b.z); o[7] = f2bf(b.w);
  *(ushort8*)(Wb + g) = o;
}

// ---------------- kernel 1: fused QKV projection ----------------------------
#define QK_SCALE 0.127517446f  // (1/sqrt(128)) * log2(e)

__global__ __launch_bounds__(256, 2) void qkv_proj_kernel(const float* __restrict__ x,
                                                          const u16* __restrict__ Wb,
                                                          u16* __restrict__ qout,
                                                          u16* __restrict__ kout,
                                                          u16* __restrict__ vtout) {
  __shared__ __align__(16) unsigned char Wlds[2][24576];  // [192][64] bf16 swz
  __shared__ __align__(16) unsigned char Xlds[2][8192];   // [64][64] bf16 swz
  const int tid = threadIdx.x;
  const int w = tid >> 6;
  const int l = tid & 63;
  const int h = l >> 5, n32 = l & 31;
  const int wm = w >> 1, wn = w & 1;
  const int bx = (int)blockIdx.x;
  const int ns = (bx >> 3) & 1;
  const int mt = (bx >> 4) * 8 + (bx & 7);   // 0..255
  const int m0 = mt * 64;

  const int xr = tid >> 2, xc = tid & 3;
  const float* xsrc = x + (size_t)(m0 + xr) * 1024 + xc * 16;
  const int xsw = (xr & 7) << 4;
  const int xo0 = xr * 128 + ((xc * 32) ^ xsw);
  const int xo1 = xr * 128 + ((xc * 32 + 16) ^ xsw);
  const u16* wg[6];
  int wo[6];
#pragma unroll
  for (int c = 0; c < 6; ++c) {
    int L = c * 256 + tid;
    int row = L >> 3, chp = L & 7;
    wg[c] = Wb + (size_t)(ns * 192 + row) * 1024 + chp * 8;
    wo[c] = row * 128 + ((chp * 16) ^ ((row & 7) << 4));
  }

  f32x16 acc[3];
#pragma unroll
  for (int j = 0; j < 3; ++j)
#pragma unroll
    for (int r = 0; r < 16; ++r) acc[j][r] = 0.f;

#define LOADS(S, k)                                                            \
  x##S##0 = *(const float4*)(xsrc + (k) * 64);                                 \
  x##S##1 = *(const float4*)(xsrc + (k) * 64 + 4);                             \
  x##S##2 = *(const float4*)(xsrc + (k) * 64 + 8);                             \
  x##S##3 = *(const float4*)(xsrc + (k) * 64 + 12);                            \
  w##S##0 = *(const ushort8*)(wg[0] + (k) * 64);                               \
  w##S##1 = *(const ushort8*)(wg[1] + (k) * 64);                               \
  w##S##2 = *(const ushort8*)(wg[2] + (k) * 64);                               \
  w##S##3 = *(const ushort8*)(wg[3] + (k) * 64);                               \
  w##S##4 = *(const ushort8*)(wg[4] + (k) * 64);                               \
  w##S##5 = *(const ushort8*)(wg[5] + (k) * 64);

#define WRITES(S, buf)                                                         \
  {                                                                            \
    float4 t0 = x##S##0;                                                       \
    float4 t1 = x##S##1;                                                       \
    float4 t2 = x##S##2;                                                       \
    float4 t3 = x##S##3;                                                       \
    ushort8 u0 = w##S##0;                                                      \
    ushort8 u1 = w##S##1;                                                      \
    ushort8 u2 = w##S##2;                                                      \
    ushort8 u3 = w##S##3;                                                      \
    ushort8 u4 = w##S##4;                                                      \
    ushort8 u5 = w##S##5;                                                      \
    int4v p0, p1;                                                              \
    p0[0] = (int)cvtpk(t0.x, t0.y);                                            \
    p0[1] = (int)cvtpk(t0.z, t0.w);                                            \
    p0[2] = (int)cvtpk(t1.x, t1.y);                                            \
    p0[3] = (int)cvtpk(t1.z, t1.w);                                            \
    p1[0] = (int)cvtpk(t2.x, t2.y);                                            \
    p1[1] = (int)cvtpk(t2.z, t2.w);                                            \
    p1[2] = (int)cvtpk(t3.x, t3.y);                                            \
    p1[3] = (int)cvtpk(t3.z, t3.w);                                            \
    *(int4v*)((unsigned char*)Xlds[buf] + xo0) = p0;                           \
    *(int4v*)((unsigned char*)Xlds[buf] + xo1) = p1;                           \
    *(ushort8*)((unsigned char*)Wlds[buf] + wo[0]) = u0;                       \
    *(ushort8*)((unsigned char*)Wlds[buf] + wo[1]) = u1;                       \
    *(ushort8*)((unsigned char*)Wlds[buf] + wo[2]) = u2;                       \
    *(ushort8*)((unsigned char*)Wlds[buf] + wo[3]) = u3;                       \
    *(ushort8*)((unsigned char*)Wlds[buf] + wo[4]) = u4;                       \
    *(ushort8*)((unsigned char*)Wlds[buf] + wo[5]) = u5;                       \
  }

#define COMPUTE(buf)                                                           \
  {                                                                            \
    const char* xb0 = (const char*)Xlds[buf];                                  \
    const char* wb0 = (const char*)Wlds[buf];                                  \
    __builtin_amdgcn_s_setprio(1);                                             \
    _Pragma("unroll") for (int k16 = 0; k16 < 4; ++k16) {                      \
      short8 a = *(const short8*)(xb0 + am * 128 +                             \
                                  ((k16 * 32 + h * 16) ^ asw));                \
      _Pragma("unroll") for (int j = 0; j < 3; ++j) {                          \
        int nrow = (wn * 3 + j) * 32 + n32;                                    \
        short8 b = *(const short8*)(wb0 + nrow * 128 +                         \
                                    ((k16 * 32 + h * 16) ^ ((nrow & 7) << 4)));\
        acc[j] = MFMA32(a, b, acc[j]);                                         \
      }                                                                        \
    }                                                                          \
    __builtin_amdgcn_s_setprio(0);                                             \
  }

  const int am = wm * 32 + n32;
  const int asw = (am & 7) << 4;

  float4 xA0, xA1, xA2, xA3, xB0, xB1, xB2, xB3;
  ushort8 wA0, wA1, wA2, wA3, wA4, wA5, wB0, wB1, wB2, wB3, wB4, wB5;

  LOADS(A, 0);
  LOADS(B, 1);
  WRITES(A, 0);
  LOADS(A, 2);
  SCHEDB();

  for (int s = 0; s < 16; s += 2) {
    WAITLGKM0();
    SCHEDB();
    __builtin_amdgcn_s_barrier();
    SCHEDB();
    WRITES(B, 1);
    if (s + 3 < 16) { LOADS(B, s + 3); }
    SCHEDB();
    COMPUTE(0);
    WAITLGKM0();
    SCHEDB();
    __builtin_amdgcn_s_barrier();
    SCHEDB();
    if (s + 2 < 16) { WRITES(A, 0); }
    if (s + 4 < 16) { LOADS(A, s + 4); }
    SCHEDB();
    COMPUTE(1);
  }
#undef LOADS
#undef WRITES
#undef COMPUTE

  const int m0e = m0 + wm * 32;
#pragma unroll
  for (int j = 0; j < 3; ++j) {
    int tig = ns * 6 + wn * 3 + j;
    int gcol = tig * 32 + n32;
    if (tig < 4) {
#pragma unroll
      for (int r = 0; r < 16; ++r) {
        int row = m0e + (r & 3) + 8 * (r >> 2) + 4 * h;
        qout[(size_t)row * 128 + gcol] = f2bf(acc[j][r] * QK_SCALE);
      }
    } else if (tig < 8) {
#pragma unroll
      for (int r = 0; r < 16; ++r) {
        int row = m0e + (r & 3) + 8 * (r >> 2) + 4 * h;
        kout[(size_t)row * 128 + (gcol - 128)] = f2bf(acc[j][r]);
      }
    } else {
      int d = gcol - 256;
#pragma unroll
      for (int rq = 0; rq < 4; ++rq) {
        int t0 = m0e + rq * 8 + 4 * h;
        ushort4v o4;
#pragma unroll
        for (int i = 0; i < 4; ++i) o4[i] = f2bf(acc[j][rq * 4 + i]);
        *(ushort4v*)&vtout[(size_t)((t0 >> 12) * 128 + d) * 4096 + (t0 & 4095)] = o4;
      }
    }
  }
}

// ---------------- kernel 2: causal flash attention --------------------------
template <bool SPLIT>
__global__ __launch_bounds__(256, 2) void attn_kernel(const u16* __restrict__ qws,
                                                      const u16* __restrict__ kws,
                                                      const u16* __restrict__ vtws,
                                                      float* __restrict__ out,
                                                      float* __restrict__ opart,
                                                      float* __restrict__ mlpart) {
  __shared__ __align__(16) unsigned char Klds[2][16384];  // [64 kv][128 d] swz
  __shared__ __align__(16) unsigned char Vlds[2][16384];  // [128 d][64 kv] swz

  const int tid = threadIdx.x;
  const int w = tid >> 6;
  const int l = tid & 63;
  const int h = l >> 5, q32 = l & 31;

  int bi, qt, s_lo, s_hi, item;
  if constexpr (SPLIT) {
    // m204 bijective chunked XCD swizzle: NITEMS=476 -> q=59, r=4.
    int bx = (int)blockIdx.x;
    int xcd = bx & 7, t = bx >> 3;
    item = (xcd < 4 ? xcd * 60 : 240 + (xcd - 4) * 59) + t;   // 0..475
    bi = item / PITEMS;
    int r = item - bi * PITEMS;
    int base = 0;
    qt = 0;
    while (true) {                          // <=32 trivial iterations
      int cnt = (qt + 5) / 5;               // ceil((qt+1)/5) chunks for tile qt
      if (r < base + cnt) { break; }
      base += cnt;
      ++qt;
    }
    int cc = r - base;
    int nsteps = 2 * qt + 2;
    s_lo = cc * CHUNK;
    s_hi = (s_lo + CHUNK < nsteps) ? s_lo + CHUNK : nsteps;
  } else {
    item = 0;
    int tb = (int)blockIdx.x;
    bi = tb & 3;
    qt = 31 - (tb >> 2);
    s_lo = 0;
    s_hi = 2 * qt + 2;
  }

  const int q0w = qt * 128 + w * 32;
  const int qg = q0w + q32;
  const int grow = bi * 4096 + qg;          // this lane's global q row
  const int ql = w * 32 + q32;              // row within the 128-row tile

  // Q B-frags resident: col=q32, k = ks*16 + 8h + e
  short8 qf[8];
  const u16* qp = qws + (size_t)grow * 128 + h * 8;
#pragma unroll
  for (int ks = 0; ks < 8; ++ks) qf[ks] = *(const short8*)(qp + ks * 16);

  f32x16 ot[4];
#pragma unroll
  for (int dt = 0; dt < 4; ++dt)
#pragma unroll
    for (int r = 0; r < 16; ++r) ot[dt][r] = 0.f;
  float mreg = NEG_INF, lsum = 0.f;

  const char* kbatch = (const char*)kws + (size_t)bi * 4096 * 256;
  const char* vbatch = (const char*)vtws + (size_t)bi * 128 * 8192;

#define STAGE_KV(buf, kv0)                                                     \
  {                                                                            \
    _Pragma("unroll") for (int c = 0; c < 4; ++c) {                            \
      int L = c * 256 + tid;                                                   \
      int row = L >> 4, chp = L & 15;                                          \
      int gch = chp ^ (row & 7);                                               \
      gload16(kbatch + (size_t)((kv0) + row) * 256 + gch * 16,                 \
              (unsigned char*)Klds[buf] + c * 4096 + w * 1024);                \
    }                                                                          \
    _Pragma("unroll") for (int c = 0; c < 4; ++c) {                            \
      int L = c * 256 + tid;                                                   \
      int row = L >> 3, chp = L & 7;                                           \
      int gch = chp ^ (row & 7);                                               \
      gload16(vbatch + (size_t)row * 8192 + (size_t)(kv0) * 2 + gch * 16,      \
              (unsigned char*)Vlds[buf] + c * 4096 + w * 1024);                \
    }                                                                          \
  }

  STAGE_KV(0, s_lo * 64);
  int cur = 0;

  for (int s = s_lo; s < s_hi; ++s) {
    WAITVM0();                       // buf(cur) landed (own loads)
    __builtin_amdgcn_s_barrier();    // all waves drained + done with buf(cur^1)
    __builtin_amdgcn_sched_barrier(0);
    if (s + 1 < s_hi) STAGE_KV(cur ^ 1, (s + 1) * 64);
    const int kv0 = s * 64;
    const bool active = (kv0 <= q0w + 31);  // wave-uniform

    if (active) {
      // ---- S^T = K · Q^T : rows kv, cols q ----
      f32x16 st0, st1;
#pragma unroll
      for (int r = 0; r < 16; ++r) { st0[r] = 0.f; st1[r] = 0.f; }
      const char* Kb = (const char*)Klds[cur];
      const int sw = (q32 & 7) << 4;
      __builtin_amdgcn_s_setprio(1);
#pragma unroll
      for (int ks = 0; ks < 8; ++ks) {
        int coff = ks * 32 + h * 16;
        short8 a0 = *(const short8*)(Kb + q32 * 256 + (coff ^ sw));
        st0 = MFMA32(a0, qf[ks], st0);
        short8 a1 = *(const short8*)(Kb + (32 + q32) * 256 + (coff ^ sw));
        st1 = MFMA32(a1, qf[ks], st1);
      }
      __builtin_amdgcn_s_setprio(0);

      // ---- causal mask: kv > q -> -inf ----
      if (kv0 + 63 > q0w) {
#pragma unroll
        for (int r = 0; r < 16; ++r) {
          int kvr = kv0 + (r & 3) + 8 * (r >> 2) + 4 * h;
          if (kvr > qg) st0[r] = NEG_INF;
          if (kvr + 32 > qg) st1[r] = NEG_INF;
        }
      }

      // ---- online softmax (exp2 domain), defer-max THR=8 ----
      float tmax = st0[0];
#pragma unroll
      for (int r = 1; r < 16; ++r) tmax = fmaxf(tmax, st0[r]);
#pragma unroll
      for (int r = 0; r < 16; ++r) tmax = fmaxf(tmax, st1[r]);
      tmax = fmaxf(tmax, __shfl_xor(tmax, 32));
      if (!__all(tmax <= mreg + 8.0f)) {
        float mnew = fmaxf(mreg, tmax);
        float alpha = exp2f(mreg - mnew);
        lsum *= alpha;
#pragma unroll
        for (int dt = 0; dt < 4; ++dt)
#pragma unroll
          for (int r = 0; r < 16; ++r) ot[dt][r] *= alpha;
        mreg = mnew;
      }
      float rs = 0.f;
#pragma unroll
      for (int r = 0; r < 16; ++r) { st0[r] = exp2f(st0[r] - mreg); rs += st0[r]; }
#pragma unroll
      for (int r = 0; r < 16; ++r) { st1[r] = exp2f(st1[r] - mreg); rs += st1[r]; }
      rs += __shfl_xor(rs, 32);
      lsum += rs;

      // ---- O^T += V^T · P^T : per kv-16 tile build P B-frag in-register ----
      const char* Vb = (const char*)Vlds[cur];
      __builtin_amdgcn_s_setprio(1);
#pragma unroll
      for (int t = 0; t < 4; ++t) {
        const f32x16& stt = (t < 2) ? st0 : st1;
        const int rb = (t & 1) * 8;
        u32 A0 = cvtpk(stt[rb + 0], stt[rb + 1]);
        u32 C0 = cvtpk(stt[rb + 2], stt[rb + 3]);
        u32 B0 = cvtpk(stt[rb + 4], stt[rb + 5]);
        u32 D0 = cvtpk(stt[rb + 6], stt[rb + 7]);
        u32 Ax = (u32)__shfl_xor((int)A0, 32);
        u32 Bx = (u32)__shfl_xor((int)B0, 32);
        u32 Cx = (u32)__shfl_xor((int)C0, 32);
        u32 Dx = (u32)__shfl_xor((int)D0, 32);
        int4v pbv;
        pbv[0] = (int)(h ? Bx : A0);
        pbv[1] = (int)(h ? Dx : C0);
        pbv[2] = (int)(h ? B0 : Ax);
        pbv[3] = (int)(h ? D0 : Cx);
        short8 pb = __builtin_bit_cast(short8, pbv);
#pragma unroll
        for (int dt = 0; dt < 4; ++dt) {
          int row = dt * 32 + q32;
          short8 va = *(const short8*)(Vb + row * 128 + ((t * 32 + h * 16) ^ sw));
          ot[dt] = MFMA32(va, pb, ot[dt]);
        }
      }
      __builtin_amdgcn_s_setprio(0);
    }
    cur ^= 1;
  }

  if constexpr (!SPLIT) {
    float inv = 1.0f / lsum;
    float* ob = out + (size_t)grow * 128;
#pragma unroll
    for (int dt = 0; dt < 4; ++dt)
#pragma unroll
      for (int rq = 0; rq < 4; ++rq) {
        f32x4 v4;
#pragma unroll
        for (int i = 0; i < 4; ++i) v4[i] = ot[dt][rq * 4 + i] * inv;
        *(f32x4*)(ob + dt * 32 + rq * 8 + 4 * h) = v4;
      }
  } else {
    float* ob = opart + (size_t)item * 16384 + (size_t)ql * 128;
#pragma unroll
    for (int dt = 0; dt < 4; ++dt)
#pragma unroll
      for (int rq = 0; rq < 4; ++rq) {
        f32x4 v4;
#pragma unroll
        for (int i = 0; i < 4; ++i) v4[i] = ot[dt][rq * 4 + i];
        *(f32x4*)(ob + dt * 32 + rq * 8 + 4 * h) = v4;
      }
    if (h == 0) {
      mlpart[item * 128 + ql] = mreg;
      mlpart[NITEMS * 128 + item * 128 + ql] = lsum;
    }
  }
#undef STAGE_KV
}

// ---------------- kernel 3: variable-split combine --------------------------
__global__ __launch_bounds__(256) void combine_kernel(const float* __restrict__ opart,
                                                      const float* __restrict__ mlpart,
                                                      float* __restrict__ out) {
  int idx = blockIdx.x * 256 + threadIdx.x;  // 16384*128 threads
  int row = idx >> 7, d = idx & 127;
  int bi = row >> 12, lrow = row & 4095;
  int qt = lrow >> 7, ql = lrow & 127;
  int base = 0;
#pragma unroll 1
  for (int j = 0; j < qt; ++j) base += (j + 5) / 5;
  int nspl = (qt + 5) / 5;
  int it0 = bi * PITEMS + base;

  float M = NEG_INF;
#pragma unroll 1
  for (int j = 0; j < nspl; ++j)
    M = fmaxf(M, mlpart[(it0 + j) * 128 + ql]);
  float L = 0.f, O = 0.f;
#pragma unroll 1
  for (int j = 0; j < nspl; ++j) {
    float s = exp2f(mlpart[(it0 + j) * 128 + ql] - M);
    L += mlpart[NITEMS * 128 + (it0 + j) * 128 + ql] * s;
    O += opart[(size_t)(it0 + j) * 16384 + (size_t)ql * 128 + d] * s;
  }
  out[(size_t)row * 128 + d] = O / L;
}

// ---------------------------------------------------------------------------
extern "C" void kernel_launch(void* const* d_in, const int* in_sizes, int n_in,
                              void* d_out, int out_size, void* d_ws, size_t ws_size,
                              hipStream_t stream) {
  (void)in_sizes; (void)n_in; (void)out_size;
  const float* x  = (const float*)d_in[0];
  const float* Wq = (const float*)d_in[1];
  const float* Wk = (const float*)d_in[2];
  const float* Wv = (const float*)d_in[3];
  float* out = (float*)d_out;
  char* ws = (char*)d_ws;
  u16* qws  = (u16*)(ws);
  u16* kws  = (u16*)(ws + (4u << 20));
  u16* vtws = (u16*)(ws + (8u << 20));
  u16* Wb   = (u16*)(ws + (12u << 20));
  float* opart  = (float*)(ws + (13u << 20));   // 476*64KB = 29.75 MiB
  float* mlpart = (float*)(ws + (47u << 20));   // 2*476*128*4B = 476 KiB

  wconv_kernel<<<dim3(192), dim3(256), 0, stream>>>(Wq, Wk, Wv, Wb);
  qkv_proj_kernel<<<dim3(512), dim3(256), 0, stream>>>(x, Wb, qws, kws, vtws);
  if (ws_size >= ((size_t)48 << 20)) {
    attn_kernel<true><<<dim3(NITEMS), dim3(256), 0, stream>>>(qws, kws, vtws, nullptr, opart, mlpart);
    combine_kernel<<<dim3(8192), dim3(256), 0, stream>>>(opart, mlpart, out);
  } else {
    attn_kernel<false><<<dim3(128), dim3(256), 0, stream>>>(qws, kws, vtws, out, nullptr, nullptr);
  }
}